// Round 18
// baseline (135.258 us; speedup 1.0000x reference)
//
#include <hip/hip_runtime.h>
#include <hip/hip_bf16.h>

typedef unsigned short u16;
typedef __attribute__((ext_vector_type(8))) short short8;
typedef __attribute__((ext_vector_type(4))) float floatx4;
typedef __attribute__((ext_vector_type(16))) float floatx16;

__device__ __forceinline__ u16 f2bf(float f) {
  union { float f; unsigned u; } v; v.f = f;
  unsigned r = v.u + 0x7fffu + ((v.u >> 16) & 1u);
  return (u16)(r >> 16);
}

__device__ __forceinline__ floatx4 mfma16(short8 a, short8 b, floatx4 c) {
  return __builtin_amdgcn_mfma_f32_16x16x32_bf16(a, b, c, 0, 0, 0);
}
__device__ __forceinline__ floatx16 mfma32(short8 a, short8 b, floatx16 c) {
  return __builtin_amdgcn_mfma_f32_32x32x16_bf16(a, b, c, 0, 0, 0);
}

#define AS1 __attribute__((address_space(1)))
#define AS3 __attribute__((address_space(3)))
__device__ __forceinline__ void gload_lds16(const u16* g, u16* l) {
  __builtin_amdgcn_global_load_lds((const AS1 void*)g, (AS3 void*)l, 16, 0, 0);
}

__device__ __forceinline__ unsigned pack2(float a, float b) {
  union { __hip_bfloat162 h; unsigned u; } x;
  x.h = __hip_bfloat162(__float2bfloat16(a), __float2bfloat16(b));
  return x.u;
}

__device__ __forceinline__ float fexp2(float x) {
#if __has_builtin(__builtin_amdgcn_exp2f)
  return __builtin_amdgcn_exp2f(x);
#else
  return exp2f(x);
#endif
}

#define WAIT_VM(N) asm volatile("s_waitcnt vmcnt(" #N ")" ::: "memory")
#define BARRIER()                      \
  do {                                 \
    __builtin_amdgcn_s_barrier();      \
    asm volatile("" ::: "memory");     \
  } while (0)

// Q is pre-scaled by 1/sqrt(64) * log2(e) so softmax runs in exp2 domain.
#define QSCALE 0.18033688f

// ---------------- prep: x f32->bf16 convert + both weight transposes ------
__global__ void __launch_bounds__(256) prep(
    const float* __restrict__ x, u16* __restrict__ Xb,
    const float* __restrict__ wqkv, u16* __restrict__ oqkv,
    const float* __restrict__ wproj, u16* __restrict__ oproj) {
  const int id = blockIdx.x;
  const int t = threadIdx.x;
  if (id < 2048) {
    const int i = id * 256 + t;
    const float4* p = (const float4*)x + (size_t)i * 2;
    float4 a = p[0], b = p[1];
    short8 o;
    o[0] = (short)f2bf(a.x); o[1] = (short)f2bf(a.y);
    o[2] = (short)f2bf(a.z); o[3] = (short)f2bf(a.w);
    o[4] = (short)f2bf(b.x); o[5] = (short)f2bf(b.y);
    o[6] = (short)f2bf(b.z); o[7] = (short)f2bf(b.w);
    *(short8*)(Xb + (size_t)i * 8) = o;
    return;
  }
  const int tid = id - 2048;
  const float* in;
  u16* out;
  int R, C, bx, by;
  if (tid < 768) {
    in = wqkv; out = oqkv; R = 1024; C = 3072;
    bx = tid % 48; by = tid / 48;
  } else {
    in = wproj; out = oproj; R = 1024; C = 1024;
    bx = (tid - 768) % 16; by = (tid - 768) / 16;
  }
  __shared__ float tile[64][65];
  const int c0 = bx * 64, r0 = by * 64;
  const int rr = t >> 2, cc = (t & 3) * 16;
  const float* src = in + (size_t)(r0 + rr) * C + (c0 + cc);
  float4 v0 = *(const float4*)(src);
  float4 v1 = *(const float4*)(src + 4);
  float4 v2 = *(const float4*)(src + 8);
  float4 v3 = *(const float4*)(src + 12);
  tile[rr][cc + 0] = v0.x;  tile[rr][cc + 1] = v0.y;
  tile[rr][cc + 2] = v0.z;  tile[rr][cc + 3] = v0.w;
  tile[rr][cc + 4] = v1.x;  tile[rr][cc + 5] = v1.y;
  tile[rr][cc + 6] = v1.z;  tile[rr][cc + 7] = v1.w;
  tile[rr][cc + 8] = v2.x;  tile[rr][cc + 9] = v2.y;
  tile[rr][cc + 10] = v2.z; tile[rr][cc + 11] = v2.w;
  tile[rr][cc + 12] = v3.x; tile[rr][cc + 13] = v3.y;
  tile[rr][cc + 14] = v3.z; tile[rr][cc + 15] = v3.w;
  __syncthreads();
  short8 w0, w1;
#pragma unroll
  for (int i = 0; i < 8; ++i) {
    w0[i] = (short)f2bf(tile[cc + i][rr]);
    w1[i] = (short)f2bf(tile[cc + 8 + i][rr]);
  }
  u16* dst = out + (size_t)(c0 + rr) * R + (r0 + cc);
  *(short8*)dst = w0;
  *(short8*)(dst + 8) = w1;
}

// ---------------- QKV GEMM: 128x128, BK=32, 2-buffer vmcnt(4) -------------
__global__ void __launch_bounds__(256) gemm_qkv(
    const u16* __restrict__ A, const u16* __restrict__ Bt,
    const float* __restrict__ bias, u16* __restrict__ O0,
    u16* __restrict__ O1, u16* __restrict__ O2, int N, int K) {
  __shared__ u16 As[2][4096];  // [buf][row*32 + slot*8], 128 rows x 64 B
  __shared__ u16 Bs[2][4096];
  const int t = threadIdx.x, w = t >> 6, l = t & 63;
  const int lo = l & 15, g = l >> 4;
  const int wr = w >> 1, wc = w & 1;
  const int m0 = blockIdx.y * 128, n0 = blockIdx.x * 128;
  const int srow = l >> 2;                       // 0..15
  const int schunk = (l & 3) ^ ((l >> 4) & 3);   // swizzled 16B chunk
  const u16* ApS = A + (size_t)(m0 + w * 32 + srow) * K + schunk * 8;
  const u16* BpS = Bt + (size_t)(n0 + w * 32 + srow) * K + schunk * 8;

  floatx4 acc[4][4] = {};
  const int NT = K >> 5;  // BK=32

#define STAGE_G(buf, kt_)                                                    \
  do {                                                                       \
    const size_t k0_ = (size_t)(kt_) * 32;                                   \
    _Pragma("unroll") for (int i = 0; i < 2; ++i)                            \
        gload_lds16(ApS + (size_t)i * 16 * K + k0_,                          \
                    &As[buf][(w * 2 + i) * 512]);                            \
    _Pragma("unroll") for (int i = 0; i < 2; ++i)                            \
        gload_lds16(BpS + (size_t)i * 16 * K + k0_,                          \
                    &Bs[buf][(w * 2 + i) * 512]);                            \
  } while (0)

#define COMPUTE_G(cur)                                                       \
  do {                                                                       \
    short8 af[4], bff[4];                                                    \
    _Pragma("unroll") for (int m = 0; m < 4; ++m) {                          \
      const int row = wr * 64 + m * 16 + lo;                                 \
      const int sl = g ^ ((lo >> 2) & 3);                                    \
      af[m] = *(const short8*)(&As[cur][row * 32 + sl * 8]);                 \
    }                                                                        \
    _Pragma("unroll") for (int n = 0; n < 4; ++n) {                          \
      const int row = wc * 64 + n * 16 + lo;                                 \
      const int sl = g ^ ((lo >> 2) & 3);                                    \
      bff[n] = *(const short8*)(&Bs[cur][row * 32 + sl * 8]);                \
    }                                                                        \
    __builtin_amdgcn_s_setprio(1);                                           \
    _Pragma("unroll") for (int m = 0; m < 4; ++m)                            \
        _Pragma("unroll") for (int n = 0; n < 4; ++n) acc[m][n] =            \
            mfma16(af[m], bff[n], acc[m][n]);                                \
    __builtin_amdgcn_s_setprio(0);                                           \
  } while (0)

  STAGE_G(0, 0);
  int cur = 0;
  for (int kt = 0; kt < NT - 1; ++kt) {
    STAGE_G(cur ^ 1, kt + 1);
    WAIT_VM(4);
    BARRIER();
    COMPUTE_G(cur);
    BARRIER();
    cur ^= 1;
  }
  WAIT_VM(0);
  BARRIER();
  COMPUTE_G(cur);
#undef STAGE_G
#undef COMPUTE_G

#pragma unroll
  for (int m = 0; m < 4; ++m) {
    const int row_base = m0 + wr * 64 + m * 16 + g * 4;
#pragma unroll
    for (int n = 0; n < 4; ++n) {
      const int col = n0 + wc * 64 + n * 16 + lo;
      const float bv = bias[col];
#pragma unroll
      for (int j = 0; j < 4; ++j) {
        const int r = row_base + j;
        const float v = acc[m][n][j] + bv;
        const int b = r >> 11, s = r & 2047;
        int c = col;
        if (c < 1024) {
          const int hh = c >> 6, d = c & 63;
          O0[(((size_t)(b * 16 + hh)) * 2048 + s) * 64 + d] = f2bf(v * QSCALE);
        } else if (c < 2048) {
          c -= 1024;
          const int hh = c >> 6, d = c & 63;
          O1[(((size_t)(b * 16 + hh)) * 2048 + s) * 64 + d] = f2bf(v);
        } else {
          c -= 2048;
          const int hh = c >> 6, d = c & 63;
          O2[(((size_t)(b * 16 + hh)) * 64 + d) * 2048 + s] = f2bf(v);
        }
      }
    }
  }
}

// ---------------- proj GEMM: 128x128 tile, BK=64, 2-buffer ----------------
__global__ void __launch_bounds__(256, 2) gemm_proj(
    const u16* __restrict__ A, const u16* __restrict__ Bt,
    const float* __restrict__ bias, float* __restrict__ Of, int N, int K) {
  __shared__ u16 As[2][8192];
  __shared__ u16 Bs[2][8192];
  const int t = threadIdx.x, w = t >> 6, l = t & 63;
  const int lo = l & 15, g = l >> 4;
  const int wr = w >> 1, wc = w & 1;
  const int m0 = blockIdx.y * 128, n0 = blockIdx.x * 128;
  const int srow = l >> 3;
  const int schunk = (l & 7) ^ srow;
  const u16* ApS = A + (size_t)(m0 + w * 32 + srow) * K + schunk * 8;
  const u16* BpS = Bt + (size_t)(n0 + w * 32 + srow) * K + schunk * 8;

  floatx4 acc[4][4] = {};
  const int NT = K >> 6;

#define STAGE_P(buf, kt_)                                                    \
  do {                                                                       \
    const size_t k0_ = (size_t)(kt_) * 64;                                   \
    _Pragma("unroll") for (int i = 0; i < 4; ++i)                            \
        gload_lds16(ApS + (size_t)i * 8 * K + k0_,                           \
                    &As[buf][(w * 4 + i) * 512]);                            \
    _Pragma("unroll") for (int i = 0; i < 4; ++i)                            \
        gload_lds16(BpS + (size_t)i * 8 * K + k0_,                           \
                    &Bs[buf][(w * 4 + i) * 512]);                            \
  } while (0)

#define COMPUTE_P(cur)                                                       \
  do {                                                                       \
    short8 af[2][4], bff[2][4];                                              \
    _Pragma("unroll") for (int kk = 0; kk < 2; ++kk)                         \
        _Pragma("unroll") for (int m = 0; m < 4; ++m) {                      \
      const int row = wr * 64 + m * 16 + lo;                                 \
      const int sl = (kk * 4 + g) ^ (row & 7);                               \
      af[kk][m] = *(const short8*)(&As[cur][row * 64 + sl * 8]);             \
    }                                                                        \
    _Pragma("unroll") for (int kk = 0; kk < 2; ++kk)                         \
        _Pragma("unroll") for (int n = 0; n < 4; ++n) {                      \
      const int row = wc * 64 + n * 16 + lo;                                 \
      const int sl = (kk * 4 + g) ^ (row & 7);                               \
      bff[kk][n] = *(const short8*)(&Bs[cur][row * 64 + sl * 8]);            \
    }                                                                        \
    __builtin_amdgcn_s_setprio(1);                                           \
    _Pragma("unroll") for (int kk = 0; kk < 2; ++kk)                         \
        _Pragma("unroll") for (int m = 0; m < 4; ++m)                        \
            _Pragma("unroll") for (int n = 0; n < 4; ++n) acc[m][n] =        \
                mfma16(af[kk][m], bff[kk][n], acc[m][n]);                    \
    __builtin_amdgcn_s_setprio(0);                                           \
  } while (0)

  STAGE_P(0, 0);
  int cur = 0;
  for (int kt = 0; kt < NT - 1; ++kt) {
    STAGE_P(cur ^ 1, kt + 1);
    WAIT_VM(8);
    BARRIER();
    COMPUTE_P(cur);
    BARRIER();
    cur ^= 1;
  }
  WAIT_VM(0);
  BARRIER();
  COMPUTE_P(cur);
#undef STAGE_P
#undef COMPUTE_P

#pragma unroll
  for (int m = 0; m < 4; ++m) {
    const int row_base = m0 + wr * 64 + m * 16 + g * 4;
#pragma unroll
    for (int n = 0; n < 4; ++n) {
      const int col = n0 + wc * 64 + n * 16 + lo;
      const float bv = bias[col];
#pragma unroll
      for (int j = 0; j < 4; ++j) {
        const int r = row_base + j;
        __builtin_nontemporal_store(acc[m][n][j] + bv,
                                    &Of[(size_t)r * N + col]);
      }
    }
  }
}

// ---------------- causal flash attention: QBLK=256, 8 waves, KVBLK=128 ----
// Each staged K/V tile feeds 8 waves (vs 4) -> per-CU staged bytes halved.
// Grid 256 = 1 block/CU; wave w owns q rows qb*256 + w*32.
__global__ void __launch_bounds__(512, 1) attn_kernel(
    const u16* __restrict__ Q, const u16* __restrict__ K,
    const u16* __restrict__ Vt, u16* __restrict__ O) {
  const int S = 2048;
  __shared__ u16 smem[2][16384];  // [buf]: K at 0, V at 8192 (u16 units)
  const int t = threadIdx.x, w = t >> 6, l = t & 63;
  const int lo = l & 31, h = l >> 5;
  const int wg = blockIdx.x;
  const int bh = wg & 31;
  const int qb = wg >> 5;  // 0..7
  const int q0w = qb * 256 + w * 32;
  const int qabs = q0w + lo;
  const u16* Qb = Q + (size_t)bh * S * 64;
  const u16* Kb = K + (size_t)bh * S * 64;
  const u16* Vb = Vt + (size_t)bh * 64 * S;

  short8 qf[4];
#pragma unroll
  for (int ks = 0; ks < 4; ++ks)
    qf[ks] = *(const short8*)(Qb + (size_t)(q0w + lo) * 64 + ks * 16 + h * 8);

  floatx16 o0 = {}, o1 = {};
  float ll = 0.f;

  auto STAGE = [&](int buf, int tile) {
    const int kv0 = tile * 128;
#pragma unroll
    for (int i = 0; i < 2; ++i) {
      const int c = i * 512 + t;
      const int rw = c >> 3;                 // 0..127
      const int cg = (c & 7) ^ (rw & 7);
      gload_lds16(Kb + (size_t)(kv0 + rw) * 64 + cg * 8,
                  &smem[buf][(i * 512 + w * 64) * 8]);
    }
#pragma unroll
    for (int i = 0; i < 2; ++i) {
      const int c = i * 512 + t;
      const int rw = c >> 4;                 // 0..63
      const int cg = (c & 15) ^ (rw & 15);
      gload_lds16(Vb + (size_t)rw * S + kv0 + cg * 8,
                  &smem[buf][8192 + (i * 512 + w * 64) * 8]);
    }
  };

  auto COMPUTE = [&](int cur, int kv0) {
    floatx16 st[4] = {};
    __builtin_amdgcn_s_setprio(1);
#pragma unroll
    for (int ks = 0; ks < 4; ++ks)
#pragma unroll
      for (int nt = 0; nt < 4; ++nt) {
        const int row = nt * 32 + lo;
        short8 kf = *(const short8*)(
            &smem[cur][row * 64 + (((ks * 2 + h) ^ (row & 7)) * 8)]);
        st[nt] = mfma32(kf, qf[ks], st[nt]);
      }
    __builtin_amdgcn_s_setprio(0);
    const bool diag = (kv0 + 127 > q0w);
#pragma unroll
    for (int nt = 0; nt < 4; ++nt) {
      float p2[16];
#pragma unroll
      for (int rr = 0; rr < 16; ++rr) {
        float v = st[nt][rr];
        if (diag) {
          const int kvr = kv0 + nt * 32 + (rr & 3) + 8 * (rr >> 2) + 4 * h;
          if (kvr > qabs) v = -1e30f;
        }
        const float e = fexp2(v);
        p2[rr] = e;
        ll += e;
      }
#pragma unroll
      for (int half = 0; half < 2; ++half) {
        const int s = nt * 2 + half, rb = half * 8;
        const unsigned wA = pack2(p2[rb + 0], p2[rb + 1]);
        const unsigned wB = pack2(p2[rb + 2], p2[rb + 3]);
        const unsigned wC = pack2(p2[rb + 4], p2[rb + 5]);
        const unsigned wD = pack2(p2[rb + 6], p2[rb + 7]);
        union { unsigned u[4]; short8 s8; } bf;
#if __has_builtin(__builtin_amdgcn_permlane32_swap)
        auto r02 = __builtin_amdgcn_permlane32_swap((int)wA, (int)wC, false, false);
        auto r13 = __builtin_amdgcn_permlane32_swap((int)wB, (int)wD, false, false);
        bf.u[0] = (unsigned)r02[0];
        bf.u[1] = (unsigned)r13[0];
        bf.u[2] = (unsigned)r02[1];
        bf.u[3] = (unsigned)r13[1];
#else
        const unsigned sA = (unsigned)__shfl_xor((int)wA, 32);
        const unsigned sB = (unsigned)__shfl_xor((int)wB, 32);
        const unsigned sC = (unsigned)__shfl_xor((int)wC, 32);
        const unsigned sD = (unsigned)__shfl_xor((int)wD, 32);
        bf.u[0] = h ? sC : wA;
        bf.u[1] = h ? sD : wB;
        bf.u[2] = h ? wC : sA;
        bf.u[3] = h ? wD : sB;
#endif
        __builtin_amdgcn_s_setprio(1);
        {
          const int d = lo;
          short8 vf = *(const short8*)(
              &smem[cur][8192 + d * 128 + (((s * 2 + h) ^ (d & 15)) * 8)]);
          o0 = mfma32(vf, bf.s8, o0);
        }
        {
          const int d = 32 + lo;
          short8 vf = *(const short8*)(
              &smem[cur][8192 + d * 128 + (((s * 2 + h) ^ (d & 15)) * 8)]);
          o1 = mfma32(vf, bf.s8, o1);
        }
        __builtin_amdgcn_s_setprio(0);
      }
    }
  };

  const int T = 2 * (qb + 1);
  STAGE(0, 0);
  int cur = 0;
  for (int tt = 0; tt < T - 1; ++tt) {
    STAGE(cur ^ 1, tt + 1);
    WAIT_VM(4);
    BARRIER();
    if (tt * 128 <= q0w + 31) COMPUTE(cur, tt * 128);
    BARRIER();
    cur ^= 1;
  }
  WAIT_VM(0);
  BARRIER();
  if ((T - 1) * 128 <= q0w + 31) COMPUTE(cur, (T - 1) * 128);
  __syncthreads();

  ll += __shfl_xor(ll, 32);
  const float rl = 1.0f / ll;
  u16* ep = &smem[0][w * 2048];
#pragma unroll
  for (int rr = 0; rr < 16; ++rr) {
    const int d0 = (rr & 3) + 8 * (rr >> 2) + 4 * h;
    ep[lo * 64 + (d0 ^ ((lo & 7) << 3))] = f2bf(o0[rr] * rl);
    const int d1 = d0 + 32;
    ep[lo * 64 + (d1 ^ ((lo & 7) << 3))] = f2bf(o1[rr] * rl);
  }
  __builtin_amdgcn_s_barrier();
  const int hh = bh & 15, b = bh >> 4;
  u16* Ob = O + ((size_t)(b * 2048 + q0w)) * 1024 + hh * 64;
#pragma unroll
  for (int pp = 0; pp < 4; ++pp) {
    const int idx = pp * 64 + l;
    const int row = idx >> 3, c = idx & 7;
    short8 v = *(const short8*)(&ep[row * 64 + ((c * 8) ^ ((row & 7) << 3))]);
    *(short8*)(Ob + (size_t)row * 1024 + c * 8) = v;
  }
}

extern "C" void kernel_launch(void* const* d_in, const int* in_sizes, int n_in,
                              void* d_out, int out_size, void* d_ws,
                              size_t ws_size, hipStream_t stream) {
  const float* x = (const float*)d_in[0];
  const float* w_qkv = (const float*)d_in[1];
  const float* b_qkv = (const float*)d_in[2];
  const float* w_proj = (const float*)d_in[3];
  const float* b_proj = (const float*)d_in[4];
  float* out = (float*)d_out;

  char* ws = (char*)d_ws;
  u16* Xb = (u16*)(ws);                      // [4096,1024] bf16  8 MB
  u16* WqkvT = (u16*)(ws + 8388608);         // [3072,1024] bf16  6 MB
  u16* WprojT = (u16*)(ws + 14680064);       // [1024,1024] bf16  2 MB
  u16* Qw = (u16*)(ws + 16777216);           // [32,2048,64] bf16 8 MB
  u16* Kw = (u16*)(ws + 25165824);           // [32,2048,64] bf16 8 MB
  u16* Vtw = (u16*)(ws + 33554432);          // [32,64,2048] bf16 8 MB
  u16* AttnO = Xb;                           // overlay: Xb dead after GEMM1

  prep<<<3072, 256, 0, stream>>>(x, Xb, w_qkv, WqkvT, w_proj, WprojT);
  gemm_qkv<<<dim3(24, 32), 256, 0, stream>>>(Xb, WqkvT, b_qkv, Qw, Kw, Vtw,
                                             3072, 1024);
  attn_kernel<<<256, 512, 0, stream>>>(Qw, Kw, Vtw, AttnO);
  gemm_proj<<<dim3(8, 32), 256, 0, stream>>>(AttnO, WprojT, b_proj, out, 1024,
                                             1024);
}

// Round 19
// 124.703 us; speedup vs baseline: 1.0846x; 1.0846x over previous
//
#include <hip/hip_runtime.h>
#include <hip/hip_bf16.h>

typedef unsigned short u16;
typedef __attribute__((ext_vector_type(8))) short short8;
typedef __attribute__((ext_vector_type(4))) float floatx4;
typedef __attribute__((ext_vector_type(16))) float floatx16;

__device__ __forceinline__ u16 f2bf(float f) {
  union { float f; unsigned u; } v; v.f = f;
  unsigned r = v.u + 0x7fffu + ((v.u >> 16) & 1u);
  return (u16)(r >> 16);
}

__device__ __forceinline__ floatx4 mfma16(short8 a, short8 b, floatx4 c) {
  return __builtin_amdgcn_mfma_f32_16x16x32_bf16(a, b, c, 0, 0, 0);
}
__device__ __forceinline__ floatx16 mfma32(short8 a, short8 b, floatx16 c) {
  return __builtin_amdgcn_mfma_f32_32x32x16_bf16(a, b, c, 0, 0, 0);
}

#define AS1 __attribute__((address_space(1)))
#define AS3 __attribute__((address_space(3)))
__device__ __forceinline__ void gload_lds16(const u16* g, u16* l) {
  __builtin_amdgcn_global_load_lds((const AS1 void*)g, (AS3 void*)l, 16, 0, 0);
}

__device__ __forceinline__ unsigned pack2(float a, float b) {
  union { __hip_bfloat162 h; unsigned u; } x;
  x.h = __hip_bfloat162(__float2bfloat16(a), __float2bfloat16(b));
  return x.u;
}

__device__ __forceinline__ float fexp2(float x) {
#if __has_builtin(__builtin_amdgcn_exp2f)
  return __builtin_amdgcn_exp2f(x);
#else
  return exp2f(x);
#endif
}

#define WAIT_VM(N) asm volatile("s_waitcnt vmcnt(" #N ")" ::: "memory")
#define BARRIER()                      \
  do {                                 \
    __builtin_amdgcn_s_barrier();      \
    asm volatile("" ::: "memory");     \
  } while (0)

// Q is pre-scaled by 1/sqrt(64) * log2(e) so softmax runs in exp2 domain.
#define QSCALE 0.18033688f

// ---------------- prep: x f32->bf16 convert + both weight transposes ------
// blocks 0..2047: convert x (8 f32/thread). 2048..2815: transpose w_qkv.
// 2816..3071: transpose w_proj.
__global__ void __launch_bounds__(256) prep(
    const float* __restrict__ x, u16* __restrict__ Xb,
    const float* __restrict__ wqkv, u16* __restrict__ oqkv,
    const float* __restrict__ wproj, u16* __restrict__ oproj) {
  const int id = blockIdx.x;
  const int t = threadIdx.x;
  if (id < 2048) {
    const int i = id * 256 + t;
    const float4* p = (const float4*)x + (size_t)i * 2;
    float4 a = p[0], b = p[1];
    short8 o;
    o[0] = (short)f2bf(a.x); o[1] = (short)f2bf(a.y);
    o[2] = (short)f2bf(a.z); o[3] = (short)f2bf(a.w);
    o[4] = (short)f2bf(b.x); o[5] = (short)f2bf(b.y);
    o[6] = (short)f2bf(b.z); o[7] = (short)f2bf(b.w);
    *(short8*)(Xb + (size_t)i * 8) = o;
    return;
  }
  const int tid = id - 2048;
  const float* in;
  u16* out;
  int R, C, bx, by;
  if (tid < 768) {
    in = wqkv; out = oqkv; R = 1024; C = 3072;
    bx = tid % 48; by = tid / 48;
  } else {
    in = wproj; out = oproj; R = 1024; C = 1024;
    bx = (tid - 768) % 16; by = (tid - 768) / 16;
  }
  __shared__ float tile[64][65];
  const int c0 = bx * 64, r0 = by * 64;
  const int rr = t >> 2, cc = (t & 3) * 16;
  const float* src = in + (size_t)(r0 + rr) * C + (c0 + cc);
  float4 v0 = *(const float4*)(src);
  float4 v1 = *(const float4*)(src + 4);
  float4 v2 = *(const float4*)(src + 8);
  float4 v3 = *(const float4*)(src + 12);
  tile[rr][cc + 0] = v0.x;  tile[rr][cc + 1] = v0.y;
  tile[rr][cc + 2] = v0.z;  tile[rr][cc + 3] = v0.w;
  tile[rr][cc + 4] = v1.x;  tile[rr][cc + 5] = v1.y;
  tile[rr][cc + 6] = v1.z;  tile[rr][cc + 7] = v1.w;
  tile[rr][cc + 8] = v2.x;  tile[rr][cc + 9] = v2.y;
  tile[rr][cc + 10] = v2.z; tile[rr][cc + 11] = v2.w;
  tile[rr][cc + 12] = v3.x; tile[rr][cc + 13] = v3.y;
  tile[rr][cc + 14] = v3.z; tile[rr][cc + 15] = v3.w;
  __syncthreads();
  short8 w0, w1;
#pragma unroll
  for (int i = 0; i < 8; ++i) {
    w0[i] = (short)f2bf(tile[cc + i][rr]);
    w1[i] = (short)f2bf(tile[cc + 8 + i][rr]);
  }
  u16* dst = out + (size_t)(c0 + rr) * R + (r0 + cc);
  *(short8*)dst = w0;
  *(short8*)(dst + 8) = w1;
}

// ---------------- QKV GEMM: 128x128, BK=32, 2-buffer vmcnt(4) -------------
// LDS 32 KB total -> ~5 blocks/CU; occupancy is the binding constraint (r13).
__global__ void __launch_bounds__(256) gemm_qkv(
    const u16* __restrict__ A, const u16* __restrict__ Bt,
    const float* __restrict__ bias, u16* __restrict__ O0,
    u16* __restrict__ O1, u16* __restrict__ O2, int N, int K) {
  __shared__ u16 As[2][4096];  // [buf][row*32 + slot*8], 128 rows x 64 B
  __shared__ u16 Bs[2][4096];
  const int t = threadIdx.x, w = t >> 6, l = t & 63;
  const int lo = l & 15, g = l >> 4;
  const int wr = w >> 1, wc = w & 1;
  const int m0 = blockIdx.y * 128, n0 = blockIdx.x * 128;
  const int srow = l >> 2;                       // 0..15
  const int schunk = (l & 3) ^ ((l >> 4) & 3);   // swizzled 16B chunk
  const u16* ApS = A + (size_t)(m0 + w * 32 + srow) * K + schunk * 8;
  const u16* BpS = Bt + (size_t)(n0 + w * 32 + srow) * K + schunk * 8;

  floatx4 acc[4][4] = {};
  const int NT = K >> 5;  // BK=32

#define STAGE_G(buf, kt_)                                                    \
  do {                                                                       \
    const size_t k0_ = (size_t)(kt_) * 32;                                   \
    _Pragma("unroll") for (int i = 0; i < 2; ++i)                            \
        gload_lds16(ApS + (size_t)i * 16 * K + k0_,                          \
                    &As[buf][(w * 2 + i) * 512]);                            \
    _Pragma("unroll") for (int i = 0; i < 2; ++i)                            \
        gload_lds16(BpS + (size_t)i * 16 * K + k0_,                          \
                    &Bs[buf][(w * 2 + i) * 512]);                            \
  } while (0)

#define COMPUTE_G(cur)                                                       \
  do {                                                                       \
    short8 af[4], bff[4];                                                    \
    _Pragma("unroll") for (int m = 0; m < 4; ++m) {                          \
      const int row = wr * 64 + m * 16 + lo;                                 \
      const int sl = g ^ ((lo >> 2) & 3);                                    \
      af[m] = *(const short8*)(&As[cur][row * 32 + sl * 8]);                 \
    }                                                                        \
    _Pragma("unroll") for (int n = 0; n < 4; ++n) {                          \
      const int row = wc * 64 + n * 16 + lo;                                 \
      const int sl = g ^ ((lo >> 2) & 3);                                    \
      bff[n] = *(const short8*)(&Bs[cur][row * 32 + sl * 8]);                \
    }                                                                        \
    __builtin_amdgcn_s_setprio(1);                                           \
    _Pragma("unroll") for (int m = 0; m < 4; ++m)                            \
        _Pragma("unroll") for (int n = 0; n < 4; ++n) acc[m][n] =            \
            mfma16(af[m], bff[n], acc[m][n]);                                \
    __builtin_amdgcn_s_setprio(0);                                           \
  } while (0)

  STAGE_G(0, 0);
  int cur = 0;
  for (int kt = 0; kt < NT - 1; ++kt) {
    STAGE_G(cur ^ 1, kt + 1);
    WAIT_VM(4);
    BARRIER();
    COMPUTE_G(cur);
    BARRIER();
    cur ^= 1;
  }
  WAIT_VM(0);
  BARRIER();
  COMPUTE_G(cur);
#undef STAGE_G
#undef COMPUTE_G

#pragma unroll
  for (int m = 0; m < 4; ++m) {
    const int row_base = m0 + wr * 64 + m * 16 + g * 4;
#pragma unroll
    for (int n = 0; n < 4; ++n) {
      const int col = n0 + wc * 64 + n * 16 + lo;
      const float bv = bias[col];
#pragma unroll
      for (int j = 0; j < 4; ++j) {
        const int r = row_base + j;
        const float v = acc[m][n][j] + bv;
        const int b = r >> 11, s = r & 2047;
        int c = col;
        if (c < 1024) {
          const int hh = c >> 6, d = c & 63;
          O0[(((size_t)(b * 16 + hh)) * 2048 + s) * 64 + d] = f2bf(v * QSCALE);
        } else if (c < 2048) {
          c -= 1024;
          const int hh = c >> 6, d = c & 63;
          O1[(((size_t)(b * 16 + hh)) * 2048 + s) * 64 + d] = f2bf(v);
        } else {
          c -= 2048;
          const int hh = c >> 6, d = c & 63;
          O2[(((size_t)(b * 16 + hh)) * 64 + d) * 2048 + s] = f2bf(v);
        }
      }
    }
  }
}

// ---------------- proj GEMM: 128x128 tile, BK=64, 2-buffer ----------------
__global__ void __launch_bounds__(256, 2) gemm_proj(
    const u16* __restrict__ A, const u16* __restrict__ Bt,
    const float* __restrict__ bias, float* __restrict__ Of, int N, int K) {
  __shared__ u16 As[2][8192];
  __shared__ u16 Bs[2][8192];
  const int t = threadIdx.x, w = t >> 6, l = t & 63;
  const int lo = l & 15, g = l >> 4;
  const int wr = w >> 1, wc = w & 1;
  const int m0 = blockIdx.y * 128, n0 = blockIdx.x * 128;
  const int srow = l >> 3;
  const int schunk = (l & 7) ^ srow;
  const u16* ApS = A + (size_t)(m0 + w * 32 + srow) * K + schunk * 8;
  const u16* BpS = Bt + (size_t)(n0 + w * 32 + srow) * K + schunk * 8;

  floatx4 acc[4][4] = {};
  const int NT = K >> 6;

#define STAGE_P(buf, kt_)                                                    \
  do {                                                                       \
    const size_t k0_ = (size_t)(kt_) * 64;                                   \
    _Pragma("unroll") for (int i = 0; i < 4; ++i)                            \
        gload_lds16(ApS + (size_t)i * 8 * K + k0_,                           \
                    &As[buf][(w * 4 + i) * 512]);                            \
    _Pragma("unroll") for (int i = 0; i < 4; ++i)                            \
        gload_lds16(BpS + (size_t)i * 8 * K + k0_,                           \
                    &Bs[buf][(w * 4 + i) * 512]);                            \
  } while (0)

#define COMPUTE_P(cur)                                                       \
  do {                                                                       \
    short8 af[2][4], bff[2][4];                                              \
    _Pragma("unroll") for (int kk = 0; kk < 2; ++kk)                         \
        _Pragma("unroll") for (int m = 0; m < 4; ++m) {                      \
      const int row = wr * 64 + m * 16 + lo;                                 \
      const int sl = (kk * 4 + g) ^ (row & 7);                               \
      af[kk][m] = *(const short8*)(&As[cur][row * 64 + sl * 8]);             \
    }                                                                        \
    _Pragma("unroll") for (int kk = 0; kk < 2; ++kk)                         \
        _Pragma("unroll") for (int n = 0; n < 4; ++n) {                      \
      const int row = wc * 64 + n * 16 + lo;                                 \
      const int sl = (kk * 4 + g) ^ (row & 7);                               \
      bff[kk][n] = *(const short8*)(&Bs[cur][row * 64 + sl * 8]);            \
    }                                                                        \
    __builtin_amdgcn_s_setprio(1);                                           \
    _Pragma("unroll") for (int kk = 0; kk < 2; ++kk)                         \
        _Pragma("unroll") for (int m = 0; m < 4; ++m)                        \
            _Pragma("unroll") for (int n = 0; n < 4; ++n) acc[m][n] =        \
                mfma16(af[kk][m], bff[kk][n], acc[m][n]);                    \
    __builtin_amdgcn_s_setprio(0);                                           \
  } while (0)

  STAGE_P(0, 0);
  int cur = 0;
  for (int kt = 0; kt < NT - 1; ++kt) {
    STAGE_P(cur ^ 1, kt + 1);
    WAIT_VM(8);
    BARRIER();
    COMPUTE_P(cur);
    BARRIER();
    cur ^= 1;
  }
  WAIT_VM(0);
  BARRIER();
  COMPUTE_P(cur);
#undef STAGE_P
#undef COMPUTE_P

#pragma unroll
  for (int m = 0; m < 4; ++m) {
    const int row_base = m0 + wr * 64 + m * 16 + g * 4;
#pragma unroll
    for (int n = 0; n < 4; ++n) {
      const int col = n0 + wc * 64 + n * 16 + lo;
      const float bv = bias[col];
#pragma unroll
      for (int j = 0; j < 4; ++j) {
        const int r = row_base + j;
        __builtin_nontemporal_store(acc[m][n][j] + bv,
                                    &Of[(size_t)r * N + col]);
      }
    }
  }
}

// ---------------- causal flash attention: KVBLK=128, fixed-base softmax ---
// r13 block mapping (best measured L2 locality). Softmax interleaved into
// PV per 32-kv slice.
__global__ void __launch_bounds__(256, 2) attn_kernel(
    const u16* __restrict__ Q, const u16* __restrict__ K,
    const u16* __restrict__ Vt, u16* __restrict__ O) {
  const int S = 2048;
  __shared__ u16 smem[2][16384];  // [buf]: K at 0, V at 8192 (u16 units)
  const int t = threadIdx.x, w = t >> 6, l = t & 63;
  const int lo = l & 31, h = l >> 5;
  const int wg = blockIdx.x;
  const int bh = (wg & 7) * 4 + ((wg >> 3) & 3);
  const int qidx = wg >> 5;
  const int qb = (qidx < 8) ? qidx : 23 - qidx;
  const int q0w = qb * 128 + w * 32;
  const int qabs = q0w + lo;
  const u16* Qb = Q + (size_t)bh * S * 64;
  const u16* Kb = K + (size_t)bh * S * 64;
  const u16* Vb = Vt + (size_t)bh * 64 * S;

  short8 qf[4];
#pragma unroll
  for (int ks = 0; ks < 4; ++ks)
    qf[ks] = *(const short8*)(Qb + (size_t)(q0w + lo) * 64 + ks * 16 + h * 8);

  floatx16 o0 = {}, o1 = {};
  float ll = 0.f;

  auto STAGE = [&](int buf, int tile) {
    const int kv0 = tile * 128;
#pragma unroll
    for (int i = 0; i < 4; ++i) {
      const int idx = i * 256 + t;
      const int rw = idx >> 3;                 // 0..127
      const int cg = (idx & 7) ^ (rw & 7);
      gload_lds16(Kb + (size_t)(kv0 + rw) * 64 + cg * 8,
                  &smem[buf][(i * 256 + w * 64) * 8]);
    }
#pragma unroll
    for (int i = 0; i < 4; ++i) {
      const int idx = i * 256 + t;
      const int rw = idx >> 4;                 // 0..63
      const int cg = (idx & 15) ^ (rw & 15);
      gload_lds16(Vb + (size_t)rw * S + kv0 + cg * 8,
                  &smem[buf][8192 + (i * 256 + w * 64) * 8]);
    }
  };

  auto COMPUTE = [&](int cur, int kv0) {
    floatx16 st[4] = {};
    __builtin_amdgcn_s_setprio(1);
#pragma unroll
    for (int ks = 0; ks < 4; ++ks)
#pragma unroll
      for (int nt = 0; nt < 4; ++nt) {
        const int row = nt * 32 + lo;
        short8 kf = *(const short8*)(
            &smem[cur][row * 64 + (((ks * 2 + h) ^ (row & 7)) * 8)]);
        st[nt] = mfma32(kf, qf[ks], st[nt]);
      }
    __builtin_amdgcn_s_setprio(0);
    const bool diag = (kv0 + 127 > q0w);
#pragma unroll
    for (int nt = 0; nt < 4; ++nt) {
      float p2[16];
#pragma unroll
      for (int rr = 0; rr < 16; ++rr) {
        float v = st[nt][rr];
        if (diag) {
          const int kvr = kv0 + nt * 32 + (rr & 3) + 8 * (rr >> 2) + 4 * h;
          if (kvr > qabs) v = -1e30f;
        }
        const float e = fexp2(v);
        p2[rr] = e;
        ll += e;
      }
#pragma unroll
      for (int half = 0; half < 2; ++half) {
        const int s = nt * 2 + half, rb = half * 8;
        const unsigned wA = pack2(p2[rb + 0], p2[rb + 1]);
        const unsigned wB = pack2(p2[rb + 2], p2[rb + 3]);
        const unsigned wC = pack2(p2[rb + 4], p2[rb + 5]);
        const unsigned wD = pack2(p2[rb + 6], p2[rb + 7]);
        union { unsigned u[4]; short8 s8; } bf;
#if __has_builtin(__builtin_amdgcn_permlane32_swap)
        auto r02 = __builtin_amdgcn_permlane32_swap((int)wA, (int)wC, false, false);
        auto r13 = __builtin_amdgcn_permlane32_swap((int)wB, (int)wD, false, false);
        bf.u[0] = (unsigned)r02[0];
        bf.u[1] = (unsigned)r13[0];
        bf.u[2] = (unsigned)r02[1];
        bf.u[3] = (unsigned)r13[1];
#else
        const unsigned sA = (unsigned)__shfl_xor((int)wA, 32);
        const unsigned sB = (unsigned)__shfl_xor((int)wB, 32);
        const unsigned sC = (unsigned)__shfl_xor((int)wC, 32);
        const unsigned sD = (unsigned)__shfl_xor((int)wD, 32);
        bf.u[0] = h ? sC : wA;
        bf.u[1] = h ? sD : wB;
        bf.u[2] = h ? wC : sA;
        bf.u[3] = h ? wD : sB;
#endif
        __builtin_amdgcn_s_setprio(1);
        {
          const int d = lo;
          short8 vf = *(const short8*)(
              &smem[cur][8192 + d * 128 + (((s * 2 + h) ^ (d & 15)) * 8)]);
          o0 = mfma32(vf, bf.s8, o0);
        }
        {
          const int d = 32 + lo;
          short8 vf = *(const short8*)(
              &smem[cur][8192 + d * 128 + (((s * 2 + h) ^ (d & 15)) * 8)]);
          o1 = mfma32(vf, bf.s8, o1);
        }
        __builtin_amdgcn_s_setprio(0);
      }
    }
  };

  const int T = qb + 1;
  STAGE(0, 0);
  int cur = 0;
  for (int tt = 0; tt < T - 1; ++tt) {
    STAGE(cur ^ 1, tt + 1);
    WAIT_VM(8);
    BARRIER();
    COMPUTE(cur, tt * 128);
    BARRIER();
    cur ^= 1;
  }
  WAIT_VM(0);
  BARRIER();
  COMPUTE(cur, (T - 1) * 128);
  __syncthreads();

  ll += __shfl_xor(ll, 32);
  const float rl = 1.0f / ll;
  u16* ep = &smem[0][w * 2048];
#pragma unroll
  for (int rr = 0; rr < 16; ++rr) {
    const int d0 = (rr & 3) + 8 * (rr >> 2) + 4 * h;
    ep[lo * 64 + (d0 ^ ((lo & 7) << 3))] = f2bf(o0[rr] * rl);
    const int d1 = d0 + 32;
    ep[lo * 64 + (d1 ^ ((lo & 7) << 3))] = f2bf(o1[rr] * rl);
  }
  __builtin_amdgcn_s_barrier();
  const int hh = bh & 15, b = bh >> 4;
  u16* Ob = O + ((size_t)(b * 2048 + q0w)) * 1024 + hh * 64;
#pragma unroll
  for (int pp = 0; pp < 4; ++pp) {
    const int idx = pp * 64 + l;
    const int row = idx >> 3, c = idx & 7;
    short8 v = *(const short8*)(&ep[row * 64 + ((c * 8) ^ ((row & 7) << 3))]);
    *(short8*)(Ob + (size_t)row * 1024 + c * 8) = v;
  }
}

extern "C" void kernel_launch(void* const* d_in, const int* in_sizes, int n_in,
                              void* d_out, int out_size, void* d_ws,
                              size_t ws_size, hipStream_t stream) {
  const float* x = (const float*)d_in[0];
  const float* w_qkv = (const float*)d_in[1];
  const float* b_qkv = (const float*)d_in[2];
  const float* w_proj = (const float*)d_in[3];
  const float* b_proj = (const float*)d_in[4];
  float* out = (float*)d_out;

  char* ws = (char*)d_ws;
  u16* Xb = (u16*)(ws);                      // [4096,1024] bf16  8 MB
  u16* WqkvT = (u16*)(ws + 8388608);         // [3072,1024] bf16  6 MB
  u16* WprojT = (u16*)(ws + 14680064);       // [1024,1024] bf16  2 MB
  u16* Qw = (u16*)(ws + 16777216);           // [32,2048,64] bf16 8 MB
  u16* Kw = (u16*)(ws + 25165824);           // [32,2048,64] bf16 8 MB
  u16* Vtw = (u16*)(ws + 33554432);          // [32,64,2048] bf16 8 MB
  u16* AttnO = Xb;                           // overlay: Xb dead after GEMM1

  prep<<<3072, 256, 0, stream>>>(x, Xb, w_qkv, WqkvT, w_proj, WprojT);
  gemm_qkv<<<dim3(24, 32), 256, 0, stream>>>(Xb, WqkvT, b_qkv, Qw, Kw, Vtw,
                                             3072, 1024);
  attn_kernel<<<512, 256, 0, stream>>>(Qw, Kw, Vtw, AttnO);
  gemm_proj<<<dim3(8, 32), 256, 0, stream>>>(AttnO, WprojT, b_proj, out, 1024,
                                             1024);
}

// Round 20
// 114.048 us; speedup vs baseline: 1.1860x; 1.0934x over previous
//
#include <hip/hip_runtime.h>
#include <hip/hip_bf16.h>

typedef unsigned short u16;
typedef __attribute__((ext_vector_type(8))) short short8;
typedef __attribute__((ext_vector_type(4))) float floatx4;
typedef __attribute__((ext_vector_type(16))) float floatx16;

__device__ __forceinline__ u16 f2bf(float f) {
  union { float f; unsigned u; } v; v.f = f;
  unsigned r = v.u + 0x7fffu + ((v.u >> 16) & 1u);
  return (u16)(r >> 16);
}

__device__ __forceinline__ floatx4 mfma16(short8 a, short8 b, floatx4 c) {
  return __builtin_amdgcn_mfma_f32_16x16x32_bf16(a, b, c, 0, 0, 0);
}
__device__ __forceinline__ floatx16 mfma32(short8 a, short8 b, floatx16 c) {
  return __builtin_amdgcn_mfma_f32_32x32x16_bf16(a, b, c, 0, 0, 0);
}

#define AS1 __attribute__((address_space(1)))
#define AS3 __attribute__((address_space(3)))
__device__ __forceinline__ void gload_lds16(const u16* g, u16* l) {
  __builtin_amdgcn_global_load_lds((const AS1 void*)g, (AS3 void*)l, 16, 0, 0);
}

__device__ __forceinline__ unsigned pack2(float a, float b) {
  union { __hip_bfloat162 h; unsigned u; } x;
  x.h = __hip_bfloat162(__float2bfloat16(a), __float2bfloat16(b));
  return x.u;
}

__device__ __forceinline__ float fexp2(float x) {
#if __has_builtin(__builtin_amdgcn_exp2f)
  return __builtin_amdgcn_exp2f(x);
#else
  return exp2f(x);
#endif
}

#define WAIT_VM(N) asm volatile("s_waitcnt vmcnt(" #N ")" ::: "memory")
#define BARRIER()                      \
  do {                                 \
    __builtin_amdgcn_s_barrier();      \
    asm volatile("" ::: "memory");     \
  } while (0)

// Q is pre-scaled by 1/sqrt(64) * log2(e) so softmax runs in exp2 domain.
#define QSCALE 0.18033688f

// ---------------- prep: x f32->bf16 convert + both weight transposes ------
__global__ void __launch_bounds__(256) prep(
    const float* __restrict__ x, u16* __restrict__ Xb,
    const float* __restrict__ wqkv, u16* __restrict__ oqkv,
    const float* __restrict__ wproj, u16* __restrict__ oproj) {
  const int id = blockIdx.x;
  const int t = threadIdx.x;
  if (id < 2048) {
    const int i = id * 256 + t;
    const float4* p = (const float4*)x + (size_t)i * 2;
    float4 a = p[0], b = p[1];
    short8 o;
    o[0] = (short)f2bf(a.x); o[1] = (short)f2bf(a.y);
    o[2] = (short)f2bf(a.z); o[3] = (short)f2bf(a.w);
    o[4] = (short)f2bf(b.x); o[5] = (short)f2bf(b.y);
    o[6] = (short)f2bf(b.z); o[7] = (short)f2bf(b.w);
    *(short8*)(Xb + (size_t)i * 8) = o;
    return;
  }
  const int tid = id - 2048;
  const float* in;
  u16* out;
  int R, C, bx, by;
  if (tid < 768) {
    in = wqkv; out = oqkv; R = 1024; C = 3072;
    bx = tid % 48; by = tid / 48;
  } else {
    in = wproj; out = oproj; R = 1024; C = 1024;
    bx = (tid - 768) % 16; by = (tid - 768) / 16;
  }
  __shared__ float tile[64][65];
  const int c0 = bx * 64, r0 = by * 64;
  const int rr = t >> 2, cc = (t & 3) * 16;
  const float* src = in + (size_t)(r0 + rr) * C + (c0 + cc);
  float4 v0 = *(const float4*)(src);
  float4 v1 = *(const float4*)(src + 4);
  float4 v2 = *(const float4*)(src + 8);
  float4 v3 = *(const float4*)(src + 12);
  tile[rr][cc + 0] = v0.x;  tile[rr][cc + 1] = v0.y;
  tile[rr][cc + 2] = v0.z;  tile[rr][cc + 3] = v0.w;
  tile[rr][cc + 4] = v1.x;  tile[rr][cc + 5] = v1.y;
  tile[rr][cc + 6] = v1.z;  tile[rr][cc + 7] = v1.w;
  tile[rr][cc + 8] = v2.x;  tile[rr][cc + 9] = v2.y;
  tile[rr][cc + 10] = v2.z; tile[rr][cc + 11] = v2.w;
  tile[rr][cc + 12] = v3.x; tile[rr][cc + 13] = v3.y;
  tile[rr][cc + 14] = v3.z; tile[rr][cc + 15] = v3.w;
  __syncthreads();
  short8 w0, w1;
#pragma unroll
  for (int i = 0; i < 8; ++i) {
    w0[i] = (short)f2bf(tile[cc + i][rr]);
    w1[i] = (short)f2bf(tile[cc + 8 + i][rr]);
  }
  u16* dst = out + (size_t)(c0 + rr) * R + (r0 + cc);
  *(short8*)dst = w0;
  *(short8*)(dst + 8) = w1;
}

// ---------------- QKV GEMM: 128x128, BK=32, 2-buffer vmcnt(4) -------------
__global__ void __launch_bounds__(256) gemm_qkv(
    const u16* __restrict__ A, const u16* __restrict__ Bt,
    const float* __restrict__ bias, u16* __restrict__ O0,
    u16* __restrict__ O1, u16* __restrict__ O2, int N, int K) {
  __shared__ u16 As[2][4096];  // [buf][row*32 + slot*8], 128 rows x 64 B
  __shared__ u16 Bs[2][4096];
  const int t = threadIdx.x, w = t >> 6, l = t & 63;
  const int lo = l & 15, g = l >> 4;
  const int wr = w >> 1, wc = w & 1;
  const int m0 = blockIdx.y * 128, n0 = blockIdx.x * 128;
  const int srow = l >> 2;                       // 0..15
  const int schunk = (l & 3) ^ ((l >> 4) & 3);   // swizzled 16B chunk
  const u16* ApS = A + (size_t)(m0 + w * 32 + srow) * K + schunk * 8;
  const u16* BpS = Bt + (size_t)(n0 + w * 32 + srow) * K + schunk * 8;

  floatx4 acc[4][4] = {};
  const int NT = K >> 5;  // BK=32

#define STAGE_G(buf, kt_)                                                    \
  do {                                                                       \
    const size_t k0_ = (size_t)(kt_) * 32;                                   \
    _Pragma("unroll") for (int i = 0; i < 2; ++i)                            \
        gload_lds16(ApS + (size_t)i * 16 * K + k0_,                          \
                    &As[buf][(w * 2 + i) * 512]);                            \
    _Pragma("unroll") for (int i = 0; i < 2; ++i)                            \
        gload_lds16(BpS + (size_t)i * 16 * K + k0_,                          \
                    &Bs[buf][(w * 2 + i) * 512]);                            \
  } while (0)

#define COMPUTE_G(cur)                                                       \
  do {                                                                       \
    short8 af[4], bff[4];                                                    \
    _Pragma("unroll") for (int m = 0; m < 4; ++m) {                          \
      const int row = wr * 64 + m * 16 + lo;                                 \
      const int sl = g ^ ((lo >> 2) & 3);                                    \
      af[m] = *(const short8*)(&As[cur][row * 32 + sl * 8]);                 \
    }                                                                        \
    _Pragma("unroll") for (int n = 0; n < 4; ++n) {                          \
      const int row = wc * 64 + n * 16 + lo;                                 \
      const int sl = g ^ ((lo >> 2) & 3);                                    \
      bff[n] = *(const short8*)(&Bs[cur][row * 32 + sl * 8]);                \
    }                                                                        \
    __builtin_amdgcn_s_setprio(1);                                           \
    _Pragma("unroll") for (int m = 0; m < 4; ++m)                            \
        _Pragma("unroll") for (int n = 0; n < 4; ++n) acc[m][n] =            \
            mfma16(af[m], bff[n], acc[m][n]);                                \
    __builtin_amdgcn_s_setprio(0);                                           \
  } while (0)

  STAGE_G(0, 0);
  int cur = 0;
  for (int kt = 0; kt < NT - 1; ++kt) {
    STAGE_G(cur ^ 1, kt + 1);
    WAIT_VM(4);
    BARRIER();
    COMPUTE_G(cur);
    BARRIER();
    cur ^= 1;
  }
  WAIT_VM(0);
  BARRIER();
  COMPUTE_G(cur);
#undef STAGE_G
#undef COMPUTE_G

#pragma unroll
  for (int m = 0; m < 4; ++m) {
    const int row_base = m0 + wr * 64 + m * 16 + g * 4;
#pragma unroll
    for (int n = 0; n < 4; ++n) {
      const int col = n0 + wc * 64 + n * 16 + lo;
      const float bv = bias[col];
#pragma unroll
      for (int j = 0; j < 4; ++j) {
        const int r = row_base + j;
        const float v = acc[m][n][j] + bv;
        const int b = r >> 11, s = r & 2047;
        int c = col;
        if (c < 1024) {
          const int hh = c >> 6, d = c & 63;
          O0[(((size_t)(b * 16 + hh)) * 2048 + s) * 64 + d] = f2bf(v * QSCALE);
        } else if (c < 2048) {
          c -= 1024;
          const int hh = c >> 6, d = c & 63;
          O1[(((size_t)(b * 16 + hh)) * 2048 + s) * 64 + d] = f2bf(v);
        } else {
          c -= 2048;
          const int hh = c >> 6, d = c & 63;
          O2[(((size_t)(b * 16 + hh)) * 64 + d) * 2048 + s] = f2bf(v);
        }
      }
    }
  }
}

// ---------------- proj GEMM: 128x128 tile, BK=64, 2-buffer ----------------
__global__ void __launch_bounds__(256, 2) gemm_proj(
    const u16* __restrict__ A, const u16* __restrict__ Bt,
    const float* __restrict__ bias, float* __restrict__ Of, int N, int K) {
  __shared__ u16 As[2][8192];
  __shared__ u16 Bs[2][8192];
  const int t = threadIdx.x, w = t >> 6, l = t & 63;
  const int lo = l & 15, g = l >> 4;
  const int wr = w >> 1, wc = w & 1;
  const int m0 = blockIdx.y * 128, n0 = blockIdx.x * 128;
  const int srow = l >> 3;
  const int schunk = (l & 7) ^ srow;
  const u16* ApS = A + (size_t)(m0 + w * 32 + srow) * K + schunk * 8;
  const u16* BpS = Bt + (size_t)(n0 + w * 32 + srow) * K + schunk * 8;

  floatx4 acc[4][4] = {};
  const int NT = K >> 6;

#define STAGE_P(buf, kt_)                                                    \
  do {                                                                       \
    const size_t k0_ = (size_t)(kt_) * 64;                                   \
    _Pragma("unroll") for (int i = 0; i < 4; ++i)                            \
        gload_lds16(ApS + (size_t)i * 8 * K + k0_,                           \
                    &As[buf][(w * 4 + i) * 512]);                            \
    _Pragma("unroll") for (int i = 0; i < 4; ++i)                            \
        gload_lds16(BpS + (size_t)i * 8 * K + k0_,                           \
                    &Bs[buf][(w * 4 + i) * 512]);                            \
  } while (0)

#define COMPUTE_P(cur)                                                       \
  do {                                                                       \
    short8 af[2][4], bff[2][4];                                              \
    _Pragma("unroll") for (int kk = 0; kk < 2; ++kk)                         \
        _Pragma("unroll") for (int m = 0; m < 4; ++m) {                      \
      const int row = wr * 64 + m * 16 + lo;                                 \
      const int sl = (kk * 4 + g) ^ (row & 7);                               \
      af[kk][m] = *(const short8*)(&As[cur][row * 64 + sl * 8]);             \
    }                                                                        \
    _Pragma("unroll") for (int kk = 0; kk < 2; ++kk)                         \
        _Pragma("unroll") for (int n = 0; n < 4; ++n) {                      \
      const int row = wc * 64 + n * 16 + lo;                                 \
      const int sl = (kk * 4 + g) ^ (row & 7);                               \
      bff[kk][n] = *(const short8*)(&Bs[cur][row * 64 + sl * 8]);            \
    }                                                                        \
    __builtin_amdgcn_s_setprio(1);                                           \
    _Pragma("unroll") for (int kk = 0; kk < 2; ++kk)                         \
        _Pragma("unroll") for (int m = 0; m < 4; ++m)                        \
            _Pragma("unroll") for (int n = 0; n < 4; ++n) acc[m][n] =        \
                mfma16(af[kk][m], bff[kk][n], acc[m][n]);                    \
    __builtin_amdgcn_s_setprio(0);                                           \
  } while (0)

  STAGE_P(0, 0);
  int cur = 0;
  for (int kt = 0; kt < NT - 1; ++kt) {
    STAGE_P(cur ^ 1, kt + 1);
    WAIT_VM(8);
    BARRIER();
    COMPUTE_P(cur);
    BARRIER();
    cur ^= 1;
  }
  WAIT_VM(0);
  BARRIER();
  COMPUTE_P(cur);
#undef STAGE_P
#undef COMPUTE_P

#pragma unroll
  for (int m = 0; m < 4; ++m) {
    const int row_base = m0 + wr * 64 + m * 16 + g * 4;
#pragma unroll
    for (int n = 0; n < 4; ++n) {
      const int col = n0 + wc * 64 + n * 16 + lo;
      const float bv = bias[col];
#pragma unroll
      for (int j = 0; j < 4; ++j) {
        const int r = row_base + j;
        __builtin_nontemporal_store(acc[m][n][j] + bv,
                                    &Of[(size_t)r * N + col]);
      }
    }
  }
}

// ---------------- causal flash attention: KVBLK=128, fixed-base softmax ---
// Diag-slice pruning: final tile is always the diagonal; wave w only needs
// nt <= w (fully-masked slices contribute exactly 0 to ll and PV). Mask
// compares only on the partial slice nt == w.
__global__ void __launch_bounds__(256, 2) attn_kernel(
    const u16* __restrict__ Q, const u16* __restrict__ K,
    const u16* __restrict__ Vt, u16* __restrict__ O) {
  const int S = 2048;
  __shared__ u16 smem[2][16384];  // [buf]: K at 0, V at 8192 (u16 units)
  const int t = threadIdx.x, w = t >> 6, l = t & 63;
  const int lo = l & 31, h = l >> 5;
  const int wg = blockIdx.x;
  const int bh = (wg & 7) * 4 + ((wg >> 3) & 3);
  const int qidx = wg >> 5;
  const int qb = (qidx < 8) ? qidx : 23 - qidx;
  const int q0w = qb * 128 + w * 32;
  const int qabs = q0w + lo;
  const u16* Qb = Q + (size_t)bh * S * 64;
  const u16* Kb = K + (size_t)bh * S * 64;
  const u16* Vb = Vt + (size_t)bh * 64 * S;

  short8 qf[4];
#pragma unroll
  for (int ks = 0; ks < 4; ++ks)
    qf[ks] = *(const short8*)(Qb + (size_t)(q0w + lo) * 64 + ks * 16 + h * 8);

  floatx16 o0 = {}, o1 = {};
  float ll = 0.f;

  auto STAGE = [&](int buf, int tile) {
    const int kv0 = tile * 128;
#pragma unroll
    for (int i = 0; i < 4; ++i) {
      const int idx = i * 256 + t;
      const int rw = idx >> 3;                 // 0..127
      const int cg = (idx & 7) ^ (rw & 7);
      gload_lds16(Kb + (size_t)(kv0 + rw) * 64 + cg * 8,
                  &smem[buf][(i * 256 + w * 64) * 8]);
    }
#pragma unroll
    for (int i = 0; i < 4; ++i) {
      const int idx = i * 256 + t;
      const int rw = idx >> 4;                 // 0..63
      const int cg = (idx & 15) ^ (rw & 15);
      gload_lds16(Vb + (size_t)rw * S + kv0 + cg * 8,
                  &smem[buf][8192 + (i * 256 + w * 64) * 8]);
    }
  };

  // ntEnd: number of 32-kv slices this wave must process (4, or w+1 on the
  // diagonal tile). Guards are wave-uniform; loops stay compile-time
  // unrolled so st[] keeps static indexing (no scratch).
  auto COMPUTE = [&](int cur, int kv0, int ntEnd) {
    floatx16 st[4] = {};
    __builtin_amdgcn_s_setprio(1);
#pragma unroll
    for (int ks = 0; ks < 4; ++ks)
#pragma unroll
      for (int nt = 0; nt < 4; ++nt)
        if (nt < ntEnd) {
          const int row = nt * 32 + lo;
          short8 kf = *(const short8*)(
              &smem[cur][row * 64 + (((ks * 2 + h) ^ (row & 7)) * 8)]);
          st[nt] = mfma32(kf, qf[ks], st[nt]);
        }
    __builtin_amdgcn_s_setprio(0);
    const bool diag = (kv0 + 127 > q0w);
#pragma unroll
    for (int nt = 0; nt < 4; ++nt) {
      if (nt >= ntEnd) continue;
      float p2[16];
      if (diag && nt == w) {
        // partial (triangular) slice: per-element mask
#pragma unroll
        for (int rr = 0; rr < 16; ++rr) {
          float v = st[nt][rr];
          const int kvr = kv0 + nt * 32 + (rr & 3) + 8 * (rr >> 2) + 4 * h;
          if (kvr > qabs) v = -1e30f;
          const float e = fexp2(v);
          p2[rr] = e;
          ll += e;
        }
      } else {
#pragma unroll
        for (int rr = 0; rr < 16; ++rr) {
          const float e = fexp2(st[nt][rr]);
          p2[rr] = e;
          ll += e;
        }
      }
#pragma unroll
      for (int half = 0; half < 2; ++half) {
        const int s = nt * 2 + half, rb = half * 8;
        const unsigned wA = pack2(p2[rb + 0], p2[rb + 1]);
        const unsigned wB = pack2(p2[rb + 2], p2[rb + 3]);
        const unsigned wC = pack2(p2[rb + 4], p2[rb + 5]);
        const unsigned wD = pack2(p2[rb + 6], p2[rb + 7]);
        union { unsigned u[4]; short8 s8; } bf;
#if __has_builtin(__builtin_amdgcn_permlane32_swap)
        auto r02 = __builtin_amdgcn_permlane32_swap((int)wA, (int)wC, false, false);
        auto r13 = __builtin_amdgcn_permlane32_swap((int)wB, (int)wD, false, false);
        bf.u[0] = (unsigned)r02[0];
        bf.u[1] = (unsigned)r13[0];
        bf.u[2] = (unsigned)r02[1];
        bf.u[3] = (unsigned)r13[1];
#else
        const unsigned sA = (unsigned)__shfl_xor((int)wA, 32);
        const unsigned sB = (unsigned)__shfl_xor((int)wB, 32);
        const unsigned sC = (unsigned)__shfl_xor((int)wC, 32);
        const unsigned sD = (unsigned)__shfl_xor((int)wD, 32);
        bf.u[0] = h ? sC : wA;
        bf.u[1] = h ? sD : wB;
        bf.u[2] = h ? wC : sA;
        bf.u[3] = h ? wD : sB;
#endif
        __builtin_amdgcn_s_setprio(1);
        {
          const int d = lo;
          short8 vf = *(const short8*)(
              &smem[cur][8192 + d * 128 + (((s * 2 + h) ^ (d & 15)) * 8)]);
          o0 = mfma32(vf, bf.s8, o0);
        }
        {
          const int d = 32 + lo;
          short8 vf = *(const short8*)(
              &smem[cur][8192 + d * 128 + (((s * 2 + h) ^ (d & 15)) * 8)]);
          o1 = mfma32(vf, bf.s8, o1);
        }
        __builtin_amdgcn_s_setprio(0);
      }
    }
  };

  const int T = qb + 1;
  STAGE(0, 0);
  int cur = 0;
  for (int tt = 0; tt < T - 1; ++tt) {
    STAGE(cur ^ 1, tt + 1);
    WAIT_VM(8);
    BARRIER();
    COMPUTE(cur, tt * 128, 4);
    BARRIER();
    cur ^= 1;
  }
  WAIT_VM(0);
  BARRIER();
  COMPUTE(cur, (T - 1) * 128, w + 1);  // final tile is the diagonal
  __syncthreads();

  ll += __shfl_xor(ll, 32);
  const float rl = 1.0f / ll;
  u16* ep = &smem[0][w * 2048];
#pragma unroll
  for (int rr = 0; rr < 16; ++rr) {
    const int d0 = (rr & 3) + 8 * (rr >> 2) + 4 * h;
    ep[lo * 64 + (d0 ^ ((lo & 7) << 3))] = f2bf(o0[rr] * rl);
    const int d1 = d0 + 32;
    ep[lo * 64 + (d1 ^ ((lo & 7) << 3))] = f2bf(o1[rr] * rl);
  }
  __builtin_amdgcn_s_barrier();
  const int hh = bh & 15, b = bh >> 4;
  u16* Ob = O + ((size_t)(b * 2048 + q0w)) * 1024 + hh * 64;
#pragma unroll
  for (int pp = 0; pp < 4; ++pp) {
    const int idx = pp * 64 + l;
    const int row = idx >> 3, c = idx & 7;
    short8 v = *(const short8*)(&ep[row * 64 + ((c * 8) ^ ((row & 7) << 3))]);
    *(short8*)(Ob + (size_t)row * 1024 + c * 8) = v;
  }
}

extern "C" void kernel_launch(void* const* d_in, const int* in_sizes, int n_in,
                              void* d_out, int out_size, void* d_ws,
                              size_t ws_size, hipStream_t stream) {
  const float* x = (const float*)d_in[0];
  const float* w_qkv = (const float*)d_in[1];
  const float* b_qkv = (const float*)d_in[2];
  const float* w_proj = (const float*)d_in[3];
  const float* b_proj = (const float*)d_in[4];
  float* out = (float*)d_out;

  char* ws = (char*)d_ws;
  u16* Xb = (u16*)(ws);                      // [4096,1024] bf16  8 MB
  u16* WqkvT = (u16*)(ws + 8388608);         // [3072,1024] bf16  6 MB
  u16* WprojT = (u16*)(ws + 14680064);       // [1024,1024] bf16  2 MB
  u16* Qw = (u16*)(ws + 16777216);           // [32,2048,64] bf16 8 MB
  u16* Kw = (u16*)(ws + 25165824);           // [32,2048,64] bf16 8 MB
  u16* Vtw = (u16*)(ws + 33554432);          // [32,64,2048] bf16 8 MB
  u16* AttnO = Xb;                           // overlay: Xb dead after GEMM1

  prep<<<3072, 256, 0, stream>>>(x, Xb, w_qkv, WqkvT, w_proj, WprojT);
  gemm_qkv<<<dim3(24, 32), 256, 0, stream>>>(Xb, WqkvT, b_qkv, Qw, Kw, Vtw,
                                             3072, 1024);
  attn_kernel<<<512, 256, 0, stream>>>(Qw, Kw, Vtw, AttnO);
  gemm_proj<<<dim3(8, 32), 256, 0, stream>>>(AttnO, WprojT, b_proj, out, 1024,
                                             1024);
}

// Round 21
// 113.938 us; speedup vs baseline: 1.1871x; 1.0010x over previous
//
#include <hip/hip_runtime.h>
#include <hip/hip_bf16.h>

typedef unsigned short u16;
typedef __attribute__((ext_vector_type(8))) short short8;
typedef __attribute__((ext_vector_type(4))) float floatx4;
typedef __attribute__((ext_vector_type(16))) float floatx16;

__device__ __forceinline__ u16 f2bf(float f) {
  union { float f; unsigned u; } v; v.f = f;
  unsigned r = v.u + 0x7fffu + ((v.u >> 16) & 1u);
  return (u16)(r >> 16);
}

__device__ __forceinline__ floatx4 mfma16(short8 a, short8 b, floatx4 c) {
  return __builtin_amdgcn_mfma_f32_16x16x32_bf16(a, b, c, 0, 0, 0);
}
__device__ __forceinline__ floatx16 mfma32(short8 a, short8 b, floatx16 c) {
  return __builtin_amdgcn_mfma_f32_32x32x16_bf16(a, b, c, 0, 0, 0);
}

#define AS1 __attribute__((address_space(1)))
#define AS3 __attribute__((address_space(3)))
__device__ __forceinline__ void gload_lds16(const u16* g, u16* l) {
  __builtin_amdgcn_global_load_lds((const AS1 void*)g, (AS3 void*)l, 16, 0, 0);
}

__device__ __forceinline__ unsigned pack2(float a, float b) {
  union { __hip_bfloat162 h; unsigned u; } x;
  x.h = __hip_bfloat162(__float2bfloat16(a), __float2bfloat16(b));
  return x.u;
}

__device__ __forceinline__ float fexp2(float x) {
#if __has_builtin(__builtin_amdgcn_exp2f)
  return __builtin_amdgcn_exp2f(x);
#else
  return exp2f(x);
#endif
}

#define WAIT_VM(N) asm volatile("s_waitcnt vmcnt(" #N ")" ::: "memory")
#define BARRIER()                      \
  do {                                 \
    __builtin_amdgcn_s_barrier();      \
    asm volatile("" ::: "memory");     \
  } while (0)

// Q is pre-scaled by 1/sqrt(64) * log2(e) so softmax runs in exp2 domain.
#define QSCALE 0.18033688f

// ---------------- prep: x f32->bf16 convert + both weight transposes ------
__global__ void __launch_bounds__(256) prep(
    const float* __restrict__ x, u16* __restrict__ Xb,
    const float* __restrict__ wqkv, u16* __restrict__ oqkv,
    const float* __restrict__ wproj, u16* __restrict__ oproj) {
  const int id = blockIdx.x;
  const int t = threadIdx.x;
  if (id < 2048) {
    const int i = id * 256 + t;
    const float4* p = (const float4*)x + (size_t)i * 2;
    float4 a = p[0], b = p[1];
    short8 o;
    o[0] = (short)f2bf(a.x); o[1] = (short)f2bf(a.y);
    o[2] = (short)f2bf(a.z); o[3] = (short)f2bf(a.w);
    o[4] = (short)f2bf(b.x); o[5] = (short)f2bf(b.y);
    o[6] = (short)f2bf(b.z); o[7] = (short)f2bf(b.w);
    *(short8*)(Xb + (size_t)i * 8) = o;
    return;
  }
  const int tid = id - 2048;
  const float* in;
  u16* out;
  int R, C, bx, by;
  if (tid < 768) {
    in = wqkv; out = oqkv; R = 1024; C = 3072;
    bx = tid % 48; by = tid / 48;
  } else {
    in = wproj; out = oproj; R = 1024; C = 1024;
    bx = (tid - 768) % 16; by = (tid - 768) / 16;
  }
  __shared__ float tile[64][65];
  const int c0 = bx * 64, r0 = by * 64;
  const int rr = t >> 2, cc = (t & 3) * 16;
  const float* src = in + (size_t)(r0 + rr) * C + (c0 + cc);
  float4 v0 = *(const float4*)(src);
  float4 v1 = *(const float4*)(src + 4);
  float4 v2 = *(const float4*)(src + 8);
  float4 v3 = *(const float4*)(src + 12);
  tile[rr][cc + 0] = v0.x;  tile[rr][cc + 1] = v0.y;
  tile[rr][cc + 2] = v0.z;  tile[rr][cc + 3] = v0.w;
  tile[rr][cc + 4] = v1.x;  tile[rr][cc + 5] = v1.y;
  tile[rr][cc + 6] = v1.z;  tile[rr][cc + 7] = v1.w;
  tile[rr][cc + 8] = v2.x;  tile[rr][cc + 9] = v2.y;
  tile[rr][cc + 10] = v2.z; tile[rr][cc + 11] = v2.w;
  tile[rr][cc + 12] = v3.x; tile[rr][cc + 13] = v3.y;
  tile[rr][cc + 14] = v3.z; tile[rr][cc + 15] = v3.w;
  __syncthreads();
  short8 w0, w1;
#pragma unroll
  for (int i = 0; i < 8; ++i) {
    w0[i] = (short)f2bf(tile[cc + i][rr]);
    w1[i] = (short)f2bf(tile[cc + 8 + i][rr]);
  }
  u16* dst = out + (size_t)(c0 + rr) * R + (r0 + cc);
  *(short8*)dst = w0;
  *(short8*)(dst + 8) = w1;
}

// ---------------- QKV GEMM: 128x128, BK=32, 2-buffer vmcnt(4) -------------
// Bank-conflict-fixed swizzle: rows are 64 B (bank cycle = 2 rows), so the
// slot-XOR must key on row bit 1 (not bit 2). f(row) = (row>>1)&3.
__global__ void __launch_bounds__(256) gemm_qkv(
    const u16* __restrict__ A, const u16* __restrict__ Bt,
    const float* __restrict__ bias, u16* __restrict__ O0,
    u16* __restrict__ O1, u16* __restrict__ O2, int N, int K) {
  __shared__ u16 As[2][4096];  // [buf][row*32 + slot*8], 128 rows x 64 B
  __shared__ u16 Bs[2][4096];
  const int t = threadIdx.x, w = t >> 6, l = t & 63;
  const int lo = l & 15, g = l >> 4;
  const int wr = w >> 1, wc = w & 1;
  const int m0 = blockIdx.y * 128, n0 = blockIdx.x * 128;
  const int srow = l >> 2;                       // 0..15
  const int schunk = (l & 3) ^ ((l >> 3) & 3);   // inverse swizzle, f=(row>>1)&3
  const u16* ApS = A + (size_t)(m0 + w * 32 + srow) * K + schunk * 8;
  const u16* BpS = Bt + (size_t)(n0 + w * 32 + srow) * K + schunk * 8;

  floatx4 acc[4][4] = {};
  const int NT = K >> 5;  // BK=32

#define STAGE_G(buf, kt_)                                                    \
  do {                                                                       \
    const size_t k0_ = (size_t)(kt_) * 32;                                   \
    _Pragma("unroll") for (int i = 0; i < 2; ++i)                            \
        gload_lds16(ApS + (size_t)i * 16 * K + k0_,                          \
                    &As[buf][(w * 2 + i) * 512]);                            \
    _Pragma("unroll") for (int i = 0; i < 2; ++i)                            \
        gload_lds16(BpS + (size_t)i * 16 * K + k0_,                          \
                    &Bs[buf][(w * 2 + i) * 512]);                            \
  } while (0)

#define COMPUTE_G(cur)                                                       \
  do {                                                                       \
    short8 af[4], bff[4];                                                    \
    _Pragma("unroll") for (int m = 0; m < 4; ++m) {                          \
      const int row = wr * 64 + m * 16 + lo;                                 \
      const int sl = g ^ ((lo >> 1) & 3);                                    \
      af[m] = *(const short8*)(&As[cur][row * 32 + sl * 8]);                 \
    }                                                                        \
    _Pragma("unroll") for (int n = 0; n < 4; ++n) {                          \
      const int row = wc * 64 + n * 16 + lo;                                 \
      const int sl = g ^ ((lo >> 1) & 3);                                    \
      bff[n] = *(const short8*)(&Bs[cur][row * 32 + sl * 8]);                \
    }                                                                        \
    __builtin_amdgcn_s_setprio(1);                                           \
    _Pragma("unroll") for (int m = 0; m < 4; ++m)                            \
        _Pragma("unroll") for (int n = 0; n < 4; ++n) acc[m][n] =            \
            mfma16(af[m], bff[n], acc[m][n]);                                \
    __builtin_amdgcn_s_setprio(0);                                           \
  } while (0)

  STAGE_G(0, 0);
  int cur = 0;
  for (int kt = 0; kt < NT - 1; ++kt) {
    STAGE_G(cur ^ 1, kt + 1);
    WAIT_VM(4);
    BARRIER();
    COMPUTE_G(cur);
    BARRIER();
    cur ^= 1;
  }
  WAIT_VM(0);
  BARRIER();
  COMPUTE_G(cur);
#undef STAGE_G
#undef COMPUTE_G

#pragma unroll
  for (int m = 0; m < 4; ++m) {
    const int row_base = m0 + wr * 64 + m * 16 + g * 4;
#pragma unroll
    for (int n = 0; n < 4; ++n) {
      const int col = n0 + wc * 64 + n * 16 + lo;
      const float bv = bias[col];
#pragma unroll
      for (int j = 0; j < 4; ++j) {
        const int r = row_base + j;
        const float v = acc[m][n][j] + bv;
        const int b = r >> 11, s = r & 2047;
        int c = col;
        if (c < 1024) {
          const int hh = c >> 6, d = c & 63;
          O0[(((size_t)(b * 16 + hh)) * 2048 + s) * 64 + d] = f2bf(v * QSCALE);
        } else if (c < 2048) {
          c -= 1024;
          const int hh = c >> 6, d = c & 63;
          O1[(((size_t)(b * 16 + hh)) * 2048 + s) * 64 + d] = f2bf(v);
        } else {
          c -= 2048;
          const int hh = c >> 6, d = c & 63;
          O2[(((size_t)(b * 16 + hh)) * 64 + d) * 2048 + s] = f2bf(v);
        }
      }
    }
  }
}

// ---------------- proj GEMM: 128x128 tile, BK=64, 2-buffer ----------------
__global__ void __launch_bounds__(256, 2) gemm_proj(
    const u16* __restrict__ A, const u16* __restrict__ Bt,
    const float* __restrict__ bias, float* __restrict__ Of, int N, int K) {
  __shared__ u16 As[2][8192];
  __shared__ u16 Bs[2][8192];
  const int t = threadIdx.x, w = t >> 6, l = t & 63;
  const int lo = l & 15, g = l >> 4;
  const int wr = w >> 1, wc = w & 1;
  const int m0 = blockIdx.y * 128, n0 = blockIdx.x * 128;
  const int srow = l >> 3;
  const int schunk = (l & 7) ^ srow;
  const u16* ApS = A + (size_t)(m0 + w * 32 + srow) * K + schunk * 8;
  const u16* BpS = Bt + (size_t)(n0 + w * 32 + srow) * K + schunk * 8;

  floatx4 acc[4][4] = {};
  const int NT = K >> 6;

#define STAGE_P(buf, kt_)                                                    \
  do {                                                                       \
    const size_t k0_ = (size_t)(kt_) * 64;                                   \
    _Pragma("unroll") for (int i = 0; i < 4; ++i)                            \
        gload_lds16(ApS + (size_t)i * 8 * K + k0_,                           \
                    &As[buf][(w * 4 + i) * 512]);                            \
    _Pragma("unroll") for (int i = 0; i < 4; ++i)                            \
        gload_lds16(BpS + (size_t)i * 8 * K + k0_,                           \
                    &Bs[buf][(w * 4 + i) * 512]);                            \
  } while (0)

#define COMPUTE_P(cur)                                                       \
  do {                                                                       \
    short8 af[2][4], bff[2][4];                                              \
    _Pragma("unroll") for (int kk = 0; kk < 2; ++kk)                         \
        _Pragma("unroll") for (int m = 0; m < 4; ++m) {                      \
      const int row = wr * 64 + m * 16 + lo;                                 \
      const int sl = (kk * 4 + g) ^ (row & 7);                               \
      af[kk][m] = *(const short8*)(&As[cur][row * 64 + sl * 8]);             \
    }                                                                        \
    _Pragma("unroll") for (int kk = 0; kk < 2; ++kk)                         \
        _Pragma("unroll") for (int n = 0; n < 4; ++n) {                      \
      const int row = wc * 64 + n * 16 + lo;                                 \
      const int sl = (kk * 4 + g) ^ (row & 7);                               \
      bff[kk][n] = *(const short8*)(&Bs[cur][row * 64 + sl * 8]);            \
    }                                                                        \
    __builtin_amdgcn_s_setprio(1);                                           \
    _Pragma("unroll") for (int kk = 0; kk < 2; ++kk)                         \
        _Pragma("unroll") for (int m = 0; m < 4; ++m)                        \
            _Pragma("unroll") for (int n = 0; n < 4; ++n) acc[m][n] =        \
                mfma16(af[kk][m], bff[kk][n], acc[m][n]);                    \
    __builtin_amdgcn_s_setprio(0);                                           \
  } while (0)

  STAGE_P(0, 0);
  int cur = 0;
  for (int kt = 0; kt < NT - 1; ++kt) {
    STAGE_P(cur ^ 1, kt + 1);
    WAIT_VM(8);
    BARRIER();
    COMPUTE_P(cur);
    BARRIER();
    cur ^= 1;
  }
  WAIT_VM(0);
  BARRIER();
  COMPUTE_P(cur);
#undef STAGE_P
#undef COMPUTE_P

#pragma unroll
  for (int m = 0; m < 4; ++m) {
    const int row_base = m0 + wr * 64 + m * 16 + g * 4;
#pragma unroll
    for (int n = 0; n < 4; ++n) {
      const int col = n0 + wc * 64 + n * 16 + lo;
      const float bv = bias[col];
#pragma unroll
      for (int j = 0; j < 4; ++j) {
        const int r = row_base + j;
        __builtin_nontemporal_store(acc[m][n][j] + bv,
                                    &Of[(size_t)r * N + col]);
      }
    }
  }
}

// ---------------- causal flash attention: KVBLK=128, fixed-base softmax ---
// Diag-slice pruning: final tile is always the diagonal; wave w only needs
// nt <= w (fully-masked slices contribute exactly 0 to ll and PV).
__global__ void __launch_bounds__(256, 2) attn_kernel(
    const u16* __restrict__ Q, const u16* __restrict__ K,
    const u16* __restrict__ Vt, u16* __restrict__ O) {
  const int S = 2048;
  __shared__ u16 smem[2][16384];  // [buf]: K at 0, V at 8192 (u16 units)
  const int t = threadIdx.x, w = t >> 6, l = t & 63;
  const int lo = l & 31, h = l >> 5;
  const int wg = blockIdx.x;
  const int bh = (wg & 7) * 4 + ((wg >> 3) & 3);
  const int qidx = wg >> 5;
  const int qb = (qidx < 8) ? qidx : 23 - qidx;
  const int q0w = qb * 128 + w * 32;
  const int qabs = q0w + lo;
  const u16* Qb = Q + (size_t)bh * S * 64;
  const u16* Kb = K + (size_t)bh * S * 64;
  const u16* Vb = Vt + (size_t)bh * 64 * S;

  short8 qf[4];
#pragma unroll
  for (int ks = 0; ks < 4; ++ks)
    qf[ks] = *(const short8*)(Qb + (size_t)(q0w + lo) * 64 + ks * 16 + h * 8);

  floatx16 o0 = {}, o1 = {};
  float ll = 0.f;

  auto STAGE = [&](int buf, int tile) {
    const int kv0 = tile * 128;
#pragma unroll
    for (int i = 0; i < 4; ++i) {
      const int idx = i * 256 + t;
      const int rw = idx >> 3;                 // 0..127
      const int cg = (idx & 7) ^ (rw & 7);
      gload_lds16(Kb + (size_t)(kv0 + rw) * 64 + cg * 8,
                  &smem[buf][(i * 256 + w * 64) * 8]);
    }
#pragma unroll
    for (int i = 0; i < 4; ++i) {
      const int idx = i * 256 + t;
      const int rw = idx >> 4;                 // 0..63
      const int cg = (idx & 15) ^ (rw & 15);
      gload_lds16(Vb + (size_t)rw * S + kv0 + cg * 8,
                  &smem[buf][8192 + (i * 256 + w * 64) * 8]);
    }
  };

  auto COMPUTE = [&](int cur, int kv0, int ntEnd) {
    floatx16 st[4] = {};
    __builtin_amdgcn_s_setprio(1);
#pragma unroll
    for (int ks = 0; ks < 4; ++ks)
#pragma unroll
      for (int nt = 0; nt < 4; ++nt)
        if (nt < ntEnd) {
          const int row = nt * 32 + lo;
          short8 kf = *(const short8*)(
              &smem[cur][row * 64 + (((ks * 2 + h) ^ (row & 7)) * 8)]);
          st[nt] = mfma32(kf, qf[ks], st[nt]);
        }
    __builtin_amdgcn_s_setprio(0);
    const bool diag = (kv0 + 127 > q0w);
#pragma unroll
    for (int nt = 0; nt < 4; ++nt) {
      if (nt >= ntEnd) continue;
      float p2[16];
      if (diag && nt == w) {
#pragma unroll
        for (int rr = 0; rr < 16; ++rr) {
          float v = st[nt][rr];
          const int kvr = kv0 + nt * 32 + (rr & 3) + 8 * (rr >> 2) + 4 * h;
          if (kvr > qabs) v = -1e30f;
          const float e = fexp2(v);
          p2[rr] = e;
          ll += e;
        }
      } else {
#pragma unroll
        for (int rr = 0; rr < 16; ++rr) {
          const float e = fexp2(st[nt][rr]);
          p2[rr] = e;
          ll += e;
        }
      }
#pragma unroll
      for (int half = 0; half < 2; ++half) {
        const int s = nt * 2 + half, rb = half * 8;
        const unsigned wA = pack2(p2[rb + 0], p2[rb + 1]);
        const unsigned wB = pack2(p2[rb + 2], p2[rb + 3]);
        const unsigned wC = pack2(p2[rb + 4], p2[rb + 5]);
        const unsigned wD = pack2(p2[rb + 6], p2[rb + 7]);
        union { unsigned u[4]; short8 s8; } bf;
#if __has_builtin(__builtin_amdgcn_permlane32_swap)
        auto r02 = __builtin_amdgcn_permlane32_swap((int)wA, (int)wC, false, false);
        auto r13 = __builtin_amdgcn_permlane32_swap((int)wB, (int)wD, false, false);
        bf.u[0] = (unsigned)r02[0];
        bf.u[1] = (unsigned)r13[0];
        bf.u[2] = (unsigned)r02[1];
        bf.u[3] = (unsigned)r13[1];
#else
        const unsigned sA = (unsigned)__shfl_xor((int)wA, 32);
        const unsigned sB = (unsigned)__shfl_xor((int)wB, 32);
        const unsigned sC = (unsigned)__shfl_xor((int)wC, 32);
        const unsigned sD = (unsigned)__shfl_xor((int)wD, 32);
        bf.u[0] = h ? sC : wA;
        bf.u[1] = h ? sD : wB;
        bf.u[2] = h ? wC : sA;
        bf.u[3] = h ? wD : sB;
#endif
        __builtin_amdgcn_s_setprio(1);
        {
          const int d = lo;
          short8 vf = *(const short8*)(
              &smem[cur][8192 + d * 128 + (((s * 2 + h) ^ (d & 15)) * 8)]);
          o0 = mfma32(vf, bf.s8, o0);
        }
        {
          const int d = 32 + lo;
          short8 vf = *(const short8*)(
              &smem[cur][8192 + d * 128 + (((s * 2 + h) ^ (d & 15)) * 8)]);
          o1 = mfma32(vf, bf.s8, o1);
        }
        __builtin_amdgcn_s_setprio(0);
      }
    }
  };

  const int T = qb + 1;
  STAGE(0, 0);
  int cur = 0;
  for (int tt = 0; tt < T - 1; ++tt) {
    STAGE(cur ^ 1, tt + 1);
    WAIT_VM(8);
    BARRIER();
    COMPUTE(cur, tt * 128, 4);
    BARRIER();
    cur ^= 1;
  }
  WAIT_VM(0);
  BARRIER();
  COMPUTE(cur, (T - 1) * 128, w + 1);  // final tile is the diagonal
  __syncthreads();

  ll += __shfl_xor(ll, 32);
  const float rl = 1.0f / ll;
  u16* ep = &smem[0][w * 2048];
#pragma unroll
  for (int rr = 0; rr < 16; ++rr) {
    const int d0 = (rr & 3) + 8 * (rr >> 2) + 4 * h;
    ep[lo * 64 + (d0 ^ ((lo & 7) << 3))] = f2bf(o0[rr] * rl);
    const int d1 = d0 + 32;
    ep[lo * 64 + (d1 ^ ((lo & 7) << 3))] = f2bf(o1[rr] * rl);
  }
  __builtin_amdgcn_s_barrier();
  const int hh = bh & 15, b = bh >> 4;
  u16* Ob = O + ((size_t)(b * 2048 + q0w)) * 1024 + hh * 64;
#pragma unroll
  for (int pp = 0; pp < 4; ++pp) {
    const int idx = pp * 64 + l;
    const int row = idx >> 3, c = idx & 7;
    short8 v = *(const short8*)(&ep[row * 64 + ((c * 8) ^ ((row & 7) << 3))]);
    *(short8*)(Ob + (size_t)row * 1024 + c * 8) = v;
  }
}

extern "C" void kernel_launch(void* const* d_in, const int* in_sizes, int n_in,
                              void* d_out, int out_size, void* d_ws,
                              size_t ws_size, hipStream_t stream) {
  const float* x = (const float*)d_in[0];
  const float* w_qkv = (const float*)d_in[1];
  const float* b_qkv = (const float*)d_in[2];
  const float* w_proj = (const float*)d_in[3];
  const float* b_proj = (const float*)d_in[4];
  float* out = (float*)d_out;

  char* ws = (char*)d_ws;
  u16* Xb = (u16*)(ws);                      // [4096,1024] bf16  8 MB
  u16* WqkvT = (u16*)(ws + 8388608);         // [3072,1024] bf16  6 MB
  u16* WprojT = (u16*)(ws + 14680064);       // [1024,1024] bf16  2 MB
  u16* Qw = (u16*)(ws + 16777216);           // [32,2048,64] bf16 8 MB
  u16* Kw = (u16*)(ws + 25165824);           // [32,2048,64] bf16 8 MB
  u16* Vtw = (u16*)(ws + 33554432);          // [32,64,2048] bf16 8 MB
  u16* AttnO = Xb;                           // overlay: Xb dead after GEMM1

  prep<<<3072, 256, 0, stream>>>(x, Xb, w_qkv, WqkvT, w_proj, WprojT);
  gemm_qkv<<<dim3(24, 32), 256, 0, stream>>>(Xb, WqkvT, b_qkv, Qw, Kw, Vtw,
                                             3072, 1024);
  attn_kernel<<<512, 256, 0, stream>>>(Qw, Kw, Vtw, AttnO);
  gemm_proj<<<dim3(8, 32), 256, 0, stream>>>(AttnO, WprojT, b_proj, out, 1024,
                                             1024);
}